// Round 4
// baseline (643.028 us; speedup 1.0000x reference)
//
#include <hip/hip_runtime.h>
#include <math.h>

// ---------------------------------------------------------------------------
// SpectralConv3d via partial DFTs. B=4, Ci=Co=32, S=64, M=12.
// Only modes k1,k2 in {0..11, 52..63}, k3 in {0..11} survive.
// Pipeline:
//   p12 : x[b,i,n1,:,:] --DFT n3(64->12), DFT n2(64->24)--> U2[b,i,n1,a2,a3]
//   p3  : DFT n1(64->24) + x_ht = U + e^{i psi} conj(U) --> XHT[b,i,a1,a2,a3]
//   per corner q: w (Yplus/Yminus), e1 (channel contraction), e2 (dht_z/n)
//   inv : per (bo,n1): zz slice -> C1(a2,k3) -> C2(n2,k3) -> out row (LDS only)
// ---------------------------------------------------------------------------

// ws layout (float offsets)
#define OFF_ES   0            // [64][2] cos/sin(2*pi*m/64)
#define OFF_C12P 128          // [12][12] cos+sin(2*pi*(k*z%12)/12)
#define OFF_C12M 272          // [12][12] sin-cos
#define OFF_U2   512
#define SZ_U2    4718592      // [128][64][24][12][2]  (forward only; never reused)
#define OFF_XHT  (OFF_U2 + SZ_U2)
#define SZ_XHT   1769472      // [128][24][24][12][2]
#define OFF_YP   (OFF_XHT + SZ_XHT)
#define SZ_Y     3538944      // [32][32][12][12][12][2] per corner (reused per q)
#define OFF_YM   (OFF_YP + SZ_Y)
#define OFF_ZB   (OFF_YM + SZ_Y)
#define SZ_ZB    442368       // [128][12][12][12][2]
#define OFF_ZZ   (OFF_ZB + SZ_ZB)
#define SZ_ZZ    884736       // [128][24][24][12] real
#define WS_FLOATS (OFF_ZZ + SZ_ZZ)   // 14,893,568 floats = ~59.6 MiB

__global__ void k_init(float* __restrict__ ws) {
    int t = threadIdx.x;
    if (t < 64) {
        double th = 6.283185307179586476925286766559 * (double)t / 64.0;
        ws[OFF_ES + 2*t]     = (float)cos(th);
        ws[OFF_ES + 2*t + 1] = (float)sin(th);
    }
    if (t < 144) {
        int k = t / 12, z = t % 12;
        double th = 6.283185307179586476925286766559 * (double)((k*z) % 12) / 12.0;
        double c = cos(th), s = sin(th);
        ws[OFF_C12P + t] = (float)(c + s);
        ws[OFF_C12M + t] = (float)(s - c);
    }
}

// P1+P2 fused: block = (bi*64 + n1). x row -> (DFT n3) -> LDS -> (DFT n2) -> U2.
// xs is stored STRAIGHT: xs[65*n2 + n3] = x[n2][n3] (65 = padded stride).
__global__ __launch_bounds__(256) void k_p12(const float* __restrict__ x,
                                             float* __restrict__ ws) {
    __shared__ float xs[65 * 64];   // xs[65*n2 + n3]
    __shared__ float us[1536];      // [n2(64)][a3(12)][2]
    __shared__ float esh[128];
    int t = threadIdx.x;
    int blk = blockIdx.x;
    const float* xrow = x + (size_t)blk * 4096;
    if (t < 128) esh[t] = ws[OFF_ES + t];
#pragma unroll
    for (int j = 0; j < 16; ++j) {
        int idx = t + 256 * j;                    // idx = n2*64 + n3
        xs[65 * (idx >> 6) + (idx & 63)] = xrow[idx];
    }
    __syncthreads();
    // P1: contract TRUE n3 (64 -> 12 modes a3), forward sign e^{-i theta}
#pragma unroll
    for (int r = 0; r < 3; ++r) {
        int oidx = t + 256 * r;             // n2*12 + a3
        int n2 = oidx / 12, a3 = oidx - n2 * 12;
        float ar = 0.f, ai = 0.f;
        int m = 0;
        const float* xr2 = &xs[65 * n2];
        for (int n3 = 0; n3 < 64; ++n3) {
            float c = esh[2*m], s = esh[2*m + 1];
            float v = xr2[n3];              // x[n2][n3]  (FIXED: was transposed)
            ar = fmaf(v, c, ar);
            ai = fmaf(-v, s, ai);
            m = (m + a3) & 63;
        }
        us[2*oidx] = ar; us[2*oidx + 1] = ai;
    }
    __syncthreads();
    // P2: contract n2 (64 -> 24 modes k2)
    float* uo = ws + OFF_U2 + (size_t)blk * 576;
    for (int r = 0; r < 2; ++r) {
        int oidx = t + 256 * r;             // a2*12 + a3
        if (oidx >= 288) break;
        int a2 = oidx / 12, a3 = oidx - a2 * 12;
        int k2 = a2 < 12 ? a2 : a2 + 40;
        float ar = 0.f, ai = 0.f;
        int m = 0;
        for (int n2 = 0; n2 < 64; ++n2) {
            float c = esh[2*m], s = esh[2*m + 1];
            float ur = us[n2*24 + 2*a3], ui = us[n2*24 + 2*a3 + 1];
            ar += ur * c + ui * s;          // (ur + i ui) * (c - i s)
            ai += ui * c - ur * s;
            m = (m + k2) & 63;
        }
        uo[2*oidx] = ar; uo[2*oidx + 1] = ai;
    }
}

// P3: contract n1 (64 -> 24) and x_ht = U + e^{i psi} conj(U), psi=2pi(k1+k2+k3)/64.
// block = bi*24 + a2.
__global__ __launch_bounds__(256) void k_p3(float* __restrict__ ws) {
    __shared__ float us[1536];      // [n1(64)][a3(12)][2]
    __shared__ float esh[128];
    int t = threadIdx.x;
    int blk = blockIdx.x;
    int bi = blk / 24, a2 = blk - bi * 24;
    const float* u2 = ws + OFF_U2;
    for (int j = t; j < 1536; j += 256) {
        int n1 = j / 24, rem = j - n1 * 24;
        us[j] = u2[(size_t)(bi * 64 + n1) * 576 + a2 * 24 + rem];
    }
    if (t < 128) esh[t] = ws[OFF_ES + t];
    __syncthreads();
    int k2 = a2 < 12 ? a2 : a2 + 40;
    float* xo = ws + OFF_XHT;
    for (int r = 0; r < 2; ++r) {
        int oidx = t + 256 * r;             // a1*12 + a3
        if (oidx >= 288) break;
        int a1 = oidx / 12, a3 = oidx - a1 * 12;
        int k1 = a1 < 12 ? a1 : a1 + 40;
        float ar = 0.f, ai = 0.f;
        int m = 0;
        for (int n1 = 0; n1 < 64; ++n1) {
            float c = esh[2*m], s = esh[2*m + 1];
            float ur = us[n1*24 + 2*a3], ui = us[n1*24 + 2*a3 + 1];
            ar += ur * c + ui * s;
            ai += ui * c - ur * s;
            m = (m + k1) & 63;
        }
        int psi = (k1 + k2 + a3) & 63;
        float pc = esh[2*psi], ps = esh[2*psi + 1];
        float xr = ar + pc * ar + ps * ai;  // U + e^{i psi} conj(U)
        float xi = ai + ps * ar - pc * ai;
        size_t o = (((size_t)bi * 24 + a1) * 24 + a2) * 12 + a3;
        xo[2*o] = xr; xo[2*o + 1] = xi;
    }
}

// W: weight prep for corner q. Y = dht_z(w_q) (real); Yflip = w_q index-negated
// over (i,o,x); Yplus/minus = 0.5*(Y +/- Yflip).  thread = (i,o,x,y,k).
__global__ __launch_bounds__(256) void k_w(const float* __restrict__ wts,
                                           float* __restrict__ ws, int q) {
    __shared__ float cp[144], cm[144];
    int t = threadIdx.x;
    if (t < 144) { cp[t] = ws[OFF_C12P + t]; cm[t] = ws[OFF_C12M + t]; }
    __syncthreads();
    int flat = blockIdx.x * 256 + t;
    int k  = flat % 12;
    int y  = (flat / 12) % 12;
    int xx = (flat / 144) % 12;
    int o  = (flat / 1728) % 32;
    int i  = flat / 55296;
    size_t wb = ((((size_t)q * 32 + i) * 32 + o) * 12 + xx) * 12 + y;
    const float* wrow = wts + wb * 24;      // 12 z * (re,im)
    float Y = 0.f;
#pragma unroll
    for (int z = 0; z < 12; ++z)
        Y += wrow[2*z] * cp[k*12 + z] + wrow[2*z + 1] * cm[k*12 + z];
    int fi = (32 - i) & 31, fo = (32 - o) & 31, fx = (xx == 0) ? 0 : 12 - xx;
    size_t fwb = (((((size_t)q * 32 + fi) * 32 + fo) * 12 + fx) * 12 + y) * 12 + k;
    float wfr = wts[2*fwb], wfi = wts[2*fwb + 1];
    float* yp = ws + OFF_YP;
    float* ym = ws + OFF_YM;
    yp[2*flat]     = 0.5f * (Y + wfr);
    yp[2*flat + 1] = 0.5f * wfi;
    ym[2*flat]     = 0.5f * (Y - wfr);
    ym[2*flat + 1] = -0.5f * wfi;
}

// E1: Z[b,o,x,y,z] = sum_i x_q*Yplus + Xflip*Yminus  (all complex).
__global__ __launch_bounds__(256) void k_e1(float* __restrict__ ws, int q) {
    int t = threadIdx.x;
    int flat = blockIdx.x * 256 + t;        // (b,o,x,y,z)
    int z  = flat % 12;
    int y  = (flat / 12) % 12;
    int xx = (flat / 144) % 12;
    int o  = (flat / 1728) % 32;
    int b  = flat / 55296;
    int o1 = (q & 1) ? 12 : 0, o2 = (q & 2) ? 12 : 0;
    const float* xht = ws + OFF_XHT;
    const float* yp  = ws + OFF_YP;
    const float* ym  = ws + OFF_YM;
    int fb = (4 - b) & 3;
    int fx = (xx == 0) ? 0 : 12 - xx;
    float zr = 0.f, zi = 0.f;
    for (int i = 0; i < 32; ++i) {
        int fi = (32 - i) & 31;
        size_t xidx  = (((size_t)(b * 32 + i) * 24 + (o1 + xx)) * 24 + (o2 + y)) * 12 + z;
        size_t fxidx = (((size_t)(fb * 32 + fi) * 24 + (o1 + fx)) * 24 + (o2 + y)) * 12 + z;
        size_t yidx  = ((((size_t)i * 32 + o) * 12 + xx) * 12 + y) * 12 + z;
        float xr = xht[2*xidx],  xi2 = xht[2*xidx + 1];
        float fr = xht[2*fxidx], fim = xht[2*fxidx + 1];
        float pr = yp[2*yidx], pi = yp[2*yidx + 1];
        float mr = ym[2*yidx], mi = ym[2*yidx + 1];
        zr += xr * pr - xi2 * pi + fr * mr - fim * mi;
        zi += xr * pi + xi2 * pr + fr * mi + fim * mr;
    }
    float* zb = ws + OFF_ZB;
    zb[2*flat] = zr; zb[2*flat + 1] = zi;
}

// E2: (Re-Im of fft12_z(Z))/n, alpha(k3) folded in, scattered into zz.
__global__ __launch_bounds__(256) void k_e2(float* __restrict__ ws, int q) {
    __shared__ float cp[144], cm[144];
    int t = threadIdx.x;
    if (t < 144) { cp[t] = ws[OFF_C12P + t]; cm[t] = ws[OFF_C12M + t]; }
    __syncthreads();
    int flat = blockIdx.x * 256 + t;        // (bo,x,y,k)
    int k  = flat % 12;
    int y  = (flat / 12) % 12;
    int xx = (flat / 144) % 12;
    int bo = flat / 1728;
    const float* row = ws + OFF_ZB + (size_t)(flat - k) * 2;  // z=0 base
    float acc = 0.f;
#pragma unroll
    for (int z = 0; z < 12; ++z)
        acc += row[2*z] * cp[k*12 + z] + row[2*z + 1] * cm[k*12 + z];
    float scale = (k == 0 ? 1.f : 2.f) / 221184.f;  // alpha(k)/n
    int o1 = (q & 1) ? 12 : 0, o2 = (q & 2) ? 12 : 0;
    float* zz = ws + OFF_ZZ;
    zz[(((size_t)bo * 24 + (o1 + xx)) * 24 + (o2 + y)) * 12 + k] = acc * scale;
}

// INV (fused i1+i2+i3): block = (bo*64 + n1). Reads ONLY zz; C1/C2 live in LDS.
//   A: C1[a2][k3] = sum_a1 zz[bo][a1][a2][k3] e^{+i 2pi k1(a1) n1/64}
//   B: C2[n2][k3] = sum_a2 C1[a2][k3]        e^{+i 2pi k2(a2) n2/64}
//   C: out[n2][n3] = (1/64^3) sum_k3 Re(C2[n2][k3] e^{+i 2pi k3 n3/64})
__global__ __launch_bounds__(256) void k_inv(const float* __restrict__ ws,
                                             float* __restrict__ out) {
    __shared__ float zs[6912];      // [a1(24)][a2(24)][k3(12)]
    __shared__ float c1s[576];      // [a2(24)][k3(12)][2]
    __shared__ float c2s[1536];     // [n2(64)][k3(12)][2]
    __shared__ float esh[128];
    int t = threadIdx.x;
    int blk = blockIdx.x;           // bo*64 + n1
    int bo = blk >> 6, n1 = blk & 63;
    if (t < 128) esh[t] = ws[OFF_ES + t];
    const float* zz = ws + OFF_ZZ + (size_t)bo * 6912;
    for (int j = t; j < 6912; j += 256) zs[j] = zz[j];
    __syncthreads();
    // A: expand a1 -> this block's n1
    for (int r = 0; r < 2; ++r) {
        int e = t + 256 * r;        // a2*12 + k3
        if (e >= 288) break;
        float re = 0.f, im = 0.f;
#pragma unroll
        for (int a1 = 0; a1 < 24; ++a1) {
            float v = zs[a1 * 288 + e];
            int k1 = a1 < 12 ? a1 : a1 + 40;
            int m = (k1 * n1) & 63;
            re += v * esh[2*m];     // e^{+i theta}
            im += v * esh[2*m + 1];
        }
        c1s[2*e] = re; c1s[2*e + 1] = im;
    }
    __syncthreads();
    // B: expand a2 -> n2
#pragma unroll
    for (int r = 0; r < 3; ++r) {
        int e = t + 256 * r;        // n2*12 + k3
        int n2 = e / 12, k3 = e - n2 * 12;
        float re = 0.f, im = 0.f;
#pragma unroll
        for (int a2 = 0; a2 < 24; ++a2) {
            float ur = c1s[a2*24 + 2*k3], ui = c1s[a2*24 + 2*k3 + 1];
            int k2 = a2 < 12 ? a2 : a2 + 40;
            int m = (k2 * n2) & 63;
            float c = esh[2*m], s = esh[2*m + 1];
            re += ur * c - ui * s;  // (ur + i ui)(c + i s)
            im += ur * s + ui * c;
        }
        c2s[2*e] = re; c2s[2*e + 1] = im;
    }
    __syncthreads();
    // C: expand k3 -> n3, take Re, scale 1/64^3
    float* orow = out + (size_t)blk * 4096;
#pragma unroll
    for (int r = 0; r < 16; ++r) {
        int f = t + 256 * r;
        int n3 = f & 63, n2 = f >> 6;
        float acc = 0.f;
        int m = 0;
#pragma unroll
        for (int k3 = 0; k3 < 12; ++k3) {
            float cr = c2s[n2*24 + 2*k3], ci = c2s[n2*24 + 2*k3 + 1];
            acc += cr * esh[2*m] - ci * esh[2*m + 1];   // Re(C2 e^{+i theta})
            m = (m + n3) & 63;
        }
        orow[f] = acc * (1.f / 262144.f);
    }
}

extern "C" void kernel_launch(void* const* d_in, const int* in_sizes, int n_in,
                              void* d_out, int out_size, void* d_ws, size_t ws_size,
                              hipStream_t stream) {
    const float* x   = (const float*)d_in[0];   // [4,32,64,64,64]
    const float* wts = (const float*)d_in[1];   // [4,32,32,12,12,12,2]
    float* out = (float*)d_out;                 // [4,32,64,64,64]
    float* ws  = (float*)d_ws;
    if (ws_size < (size_t)WS_FLOATS * sizeof(float)) return;  // insufficient scratch

    k_init<<<1, 256, 0, stream>>>(ws);
    k_p12<<<8192, 256, 0, stream>>>(x, ws);
    k_p3<<<3072, 256, 0, stream>>>(ws);
    for (int q = 0; q < 4; ++q) {
        k_w<<<6912, 256, 0, stream>>>(wts, ws, q);
        k_e1<<<864, 256, 0, stream>>>(ws, q);
        k_e2<<<864, 256, 0, stream>>>(ws, q);
    }
    k_inv<<<8192, 256, 0, stream>>>(ws, out);
}

// Round 5
// 563.063 us; speedup vs baseline: 1.1420x; 1.1420x over previous
//
#include <hip/hip_runtime.h>
#include <math.h>

// ---------------------------------------------------------------------------
// SpectralConv3d via partial DFTs. B=4, Ci=Co=32, S=64, M=12.
// Only modes k1,k2 in {0..11, 52..63}, k3 in {0..11} survive.
// Pipeline:
//   p12 : x[b,i,n1,:,:] --DFT n3(64->12), DFT n2(64->24)--> U2[b,i,n1,a2,a3]
//   p3  : DFT n1(64->24) + x_ht = U + e^{i psi} conj(U) --> XHT[b,i,a1,a2,a3]
//   per corner q: w (Yplus/Yminus), e1 (channel contraction), e2 (dht_z/n)
//   inv : per (bo,n1): zz (global, L2) -> C1(a2,k3) -> C2(n2,k3) -> out row
// ---------------------------------------------------------------------------

// ws layout (float offsets)
#define OFF_ES   0            // [64][2] cos/sin(2*pi*m/64)
#define OFF_C12P 128          // [12][12] cos+sin(2*pi*(k*z%12)/12)
#define OFF_C12M 272          // [12][12] sin-cos
#define OFF_U2   512
#define SZ_U2    4718592      // [128][64][24][12][2]  (forward only)
#define OFF_XHT  (OFF_U2 + SZ_U2)
#define SZ_XHT   1769472      // [128][24][24][12][2]
#define OFF_YP   (OFF_XHT + SZ_XHT)
#define SZ_Y     3538944      // [32][32][12][12][12][2] per corner (reused per q)
#define OFF_YM   (OFF_YP + SZ_Y)
#define OFF_ZB   (OFF_YM + SZ_Y)
#define SZ_ZB    442368       // [128][12][12][12][2]
#define OFF_ZZ   (OFF_ZB + SZ_ZB)
#define SZ_ZZ    884736       // [128][24][24][12] real
#define WS_FLOATS (OFF_ZZ + SZ_ZZ)   // 14,893,568 floats = ~59.6 MiB

__global__ void k_init(float* __restrict__ ws) {
    int t = threadIdx.x;
    if (t < 64) {
        double th = 6.283185307179586476925286766559 * (double)t / 64.0;
        ws[OFF_ES + 2*t]     = (float)cos(th);
        ws[OFF_ES + 2*t + 1] = (float)sin(th);
    }
    if (t < 144) {
        int k = t / 12, z = t % 12;
        double th = 6.283185307179586476925286766559 * (double)((k*z) % 12) / 12.0;
        double c = cos(th), s = sin(th);
        ws[OFF_C12P + t] = (float)(c + s);
        ws[OFF_C12M + t] = (float)(s - c);
    }
}

// P1+P2 fused: block = (bi*64 + n1).
// P1 outputs are a3-major so the esh twiddle address is WAVE-UNIFORM
// (a3 = oidx>>6 is constant across a wave's 64 lanes) -> broadcast, no
// conflict; each lane owns one xs row (bank = (n2+n3)%32, 2-way = free).
// us stride 26 keeps P1 writes / P2 reads conflict-free.
__global__ __launch_bounds__(256) void k_p12(const float* __restrict__ x,
                                             float* __restrict__ ws) {
    __shared__ float xs[65 * 64];   // xs[65*n2 + n3]
    __shared__ float us[64 * 26];   // [n2][a3][2], row stride 26
    __shared__ float esh[128];
    int t = threadIdx.x;
    int blk = blockIdx.x;
    const float* xrow = x + (size_t)blk * 4096;
    if (t < 128) esh[t] = ws[OFF_ES + t];
#pragma unroll
    for (int j = 0; j < 16; ++j) {
        int idx = t + 256 * j;                    // idx = n2*64 + n3
        xs[65 * (idx >> 6) + (idx & 63)] = xrow[idx];
    }
    __syncthreads();
    // P1: contract n3 (64 -> 12 modes a3), e^{-i 2pi a3 n3/64}
#pragma unroll
    for (int r = 0; r < 3; ++r) {
        int oidx = t + 256 * r;             // a3*64 + n2
        int a3 = oidx >> 6, n2 = oidx & 63;
        float ar = 0.f, ai = 0.f;
        int m = 0;
        const float* xr2 = &xs[65 * n2];
        for (int n3 = 0; n3 < 64; ++n3) {
            float c = esh[2*m], s = esh[2*m + 1];   // wave-uniform addr
            float v = xr2[n3];
            ar = fmaf(v, c, ar);
            ai = fmaf(-v, s, ai);
            m = (m + a3) & 63;
        }
        us[n2*26 + 2*a3] = ar; us[n2*26 + 2*a3 + 1] = ai;
    }
    __syncthreads();
    // P2: contract n2 (64 -> 24 modes k2)
    float* uo = ws + OFF_U2 + (size_t)blk * 576;
    for (int r = 0; r < 2; ++r) {
        int oidx = t + 256 * r;             // a2*12 + a3
        if (oidx >= 288) break;
        int a2 = oidx / 12, a3 = oidx - a2 * 12;
        int k2 = a2 < 12 ? a2 : a2 + 40;
        float ar = 0.f, ai = 0.f;
        int m = 0;
        for (int n2 = 0; n2 < 64; ++n2) {
            float c = esh[2*m], s = esh[2*m + 1];
            float ur = us[n2*26 + 2*a3], ui = us[n2*26 + 2*a3 + 1];
            ar += ur * c + ui * s;          // (ur + i ui) * (c - i s)
            ai += ui * c - ur * s;
            m = (m + k2) & 63;
        }
        uo[2*oidx] = ar; uo[2*oidx + 1] = ai;
    }
}

// P3: contract n1 (64 -> 24) and x_ht = U + e^{i psi} conj(U), psi=2pi(k1+k2+k3)/64.
// block = bi*24 + a2.
__global__ __launch_bounds__(256) void k_p3(float* __restrict__ ws) {
    __shared__ float us[1536];      // [n1(64)][a3(12)][2]
    __shared__ float esh[128];
    int t = threadIdx.x;
    int blk = blockIdx.x;
    int bi = blk / 24, a2 = blk - bi * 24;
    const float* u2 = ws + OFF_U2;
    for (int j = t; j < 1536; j += 256) {
        int n1 = j / 24, rem = j - n1 * 24;
        us[j] = u2[(size_t)(bi * 64 + n1) * 576 + a2 * 24 + rem];
    }
    if (t < 128) esh[t] = ws[OFF_ES + t];
    __syncthreads();
    int k2 = a2 < 12 ? a2 : a2 + 40;
    float* xo = ws + OFF_XHT;
    for (int r = 0; r < 2; ++r) {
        int oidx = t + 256 * r;             // a1*12 + a3
        if (oidx >= 288) break;
        int a1 = oidx / 12, a3 = oidx - a1 * 12;
        int k1 = a1 < 12 ? a1 : a1 + 40;
        float ar = 0.f, ai = 0.f;
        int m = 0;
        for (int n1 = 0; n1 < 64; ++n1) {
            float c = esh[2*m], s = esh[2*m + 1];
            float ur = us[n1*24 + 2*a3], ui = us[n1*24 + 2*a3 + 1];
            ar += ur * c + ui * s;
            ai += ui * c - ur * s;
            m = (m + k1) & 63;
        }
        int psi = (k1 + k2 + a3) & 63;
        float pc = esh[2*psi], ps = esh[2*psi + 1];
        float xr = ar + pc * ar + ps * ai;  // U + e^{i psi} conj(U)
        float xi = ai + ps * ar - pc * ai;
        size_t o = (((size_t)bi * 24 + a1) * 24 + a2) * 12 + a3;
        xo[2*o] = xr; xo[2*o + 1] = xi;
    }
}

// W: weight prep for corner q. Y = dht_z(w_q) (real); Yflip = w_q index-negated
// over (i,o,x); Yplus/minus = 0.5*(Y +/- Yflip).  thread = (i,o,x,y,k).
__global__ __launch_bounds__(256) void k_w(const float* __restrict__ wts,
                                           float* __restrict__ ws, int q) {
    __shared__ float cp[144], cm[144];
    int t = threadIdx.x;
    if (t < 144) { cp[t] = ws[OFF_C12P + t]; cm[t] = ws[OFF_C12M + t]; }
    __syncthreads();
    int flat = blockIdx.x * 256 + t;
    int k  = flat % 12;
    int y  = (flat / 12) % 12;
    int xx = (flat / 144) % 12;
    int o  = (flat / 1728) % 32;
    int i  = flat / 55296;
    size_t wb = ((((size_t)q * 32 + i) * 32 + o) * 12 + xx) * 12 + y;
    const float* wrow = wts + wb * 24;      // 12 z * (re,im)
    float Y = 0.f;
#pragma unroll
    for (int z = 0; z < 12; ++z)
        Y += wrow[2*z] * cp[k*12 + z] + wrow[2*z + 1] * cm[k*12 + z];
    int fi = (32 - i) & 31, fo = (32 - o) & 31, fx = (xx == 0) ? 0 : 12 - xx;
    size_t fwb = (((((size_t)q * 32 + fi) * 32 + fo) * 12 + fx) * 12 + y) * 12 + k;
    float wfr = wts[2*fwb], wfi = wts[2*fwb + 1];
    float* yp = ws + OFF_YP;
    float* ym = ws + OFF_YM;
    yp[2*flat]     = 0.5f * (Y + wfr);
    yp[2*flat + 1] = 0.5f * wfi;
    ym[2*flat]     = 0.5f * (Y - wfr);
    ym[2*flat + 1] = -0.5f * wfi;
}

// E1: Z[b,o,x,y,z] = sum_i x_q*Yplus + Xflip*Yminus  (all complex).
__global__ __launch_bounds__(256) void k_e1(float* __restrict__ ws, int q) {
    int t = threadIdx.x;
    int flat = blockIdx.x * 256 + t;        // (b,o,x,y,z)
    int z  = flat % 12;
    int y  = (flat / 12) % 12;
    int xx = (flat / 144) % 12;
    int o  = (flat / 1728) % 32;
    int b  = flat / 55296;
    int o1 = (q & 1) ? 12 : 0, o2 = (q & 2) ? 12 : 0;
    const float* xht = ws + OFF_XHT;
    const float* yp  = ws + OFF_YP;
    const float* ym  = ws + OFF_YM;
    int fb = (4 - b) & 3;
    int fx = (xx == 0) ? 0 : 12 - xx;
    float zr = 0.f, zi = 0.f;
    for (int i = 0; i < 32; ++i) {
        int fi = (32 - i) & 31;
        size_t xidx  = (((size_t)(b * 32 + i) * 24 + (o1 + xx)) * 24 + (o2 + y)) * 12 + z;
        size_t fxidx = (((size_t)(fb * 32 + fi) * 24 + (o1 + fx)) * 24 + (o2 + y)) * 12 + z;
        size_t yidx  = ((((size_t)i * 32 + o) * 12 + xx) * 12 + y) * 12 + z;
        float xr = xht[2*xidx],  xi2 = xht[2*xidx + 1];
        float fr = xht[2*fxidx], fim = xht[2*fxidx + 1];
        float pr = yp[2*yidx], pi = yp[2*yidx + 1];
        float mr = ym[2*yidx], mi = ym[2*yidx + 1];
        zr += xr * pr - xi2 * pi + fr * mr - fim * mi;
        zi += xr * pi + xi2 * pr + fr * mi + fim * mr;
    }
    float* zb = ws + OFF_ZB;
    zb[2*flat] = zr; zb[2*flat + 1] = zi;
}

// E2: (Re-Im of fft12_z(Z))/n, alpha(k3) folded in, scattered into zz.
__global__ __launch_bounds__(256) void k_e2(float* __restrict__ ws, int q) {
    __shared__ float cp[144], cm[144];
    int t = threadIdx.x;
    if (t < 144) { cp[t] = ws[OFF_C12P + t]; cm[t] = ws[OFF_C12M + t]; }
    __syncthreads();
    int flat = blockIdx.x * 256 + t;        // (bo,x,y,k)
    int k  = flat % 12;
    int y  = (flat / 12) % 12;
    int xx = (flat / 144) % 12;
    int bo = flat / 1728;
    const float* row = ws + OFF_ZB + (size_t)(flat - k) * 2;  // z=0 base
    float acc = 0.f;
#pragma unroll
    for (int z = 0; z < 12; ++z)
        acc += row[2*z] * cp[k*12 + z] + row[2*z + 1] * cm[k*12 + z];
    float scale = (k == 0 ? 1.f : 2.f) / 221184.f;  // alpha(k)/n
    int o1 = (q & 1) ? 12 : 0, o2 = (q & 2) ? 12 : 0;
    float* zz = ws + OFF_ZZ;
    zz[(((size_t)bo * 24 + (o1 + xx)) * 24 + (o2 + y)) * 12 + k] = acc * scale;
}

// INV: block = (bo*64 + n1). Reads zz straight from global (L2/L3-resident,
// coalesced); C1/C2 in LDS (9 KB total -> high occupancy).
//   A: C1[a2][k3] = sum_a1 zz[bo][a1][a2][k3] e^{+i 2pi k1(a1) n1/64}
//      (esh addr depends only on a1,n1 -> wave-uniform broadcast)
//   B: C2[n2][k3] = sum_a2 C1[a2][k3] e^{+i 2pi k2(a2) n2/64}
//   C: out[n2][n3] = (1/64^3) sum_k3 Re(C2[n2][k3] e^{+i 2pi k3 n3/64})
//      (twiddles hoisted to registers: n3 = t&63 invariant across rows;
//       c2s row reads wave-uniform -> broadcast)
__global__ __launch_bounds__(256) void k_inv(const float* __restrict__ ws,
                                             float* __restrict__ out) {
    __shared__ float c1s[576];      // [a2(24)][k3(12)][2]
    __shared__ float c2s[1536];     // [n2(64)][k3(12)][2]
    __shared__ float esh[128];
    int t = threadIdx.x;
    int blk = blockIdx.x;           // bo*64 + n1
    int bo = blk >> 6, n1 = blk & 63;
    if (t < 128) esh[t] = ws[OFF_ES + t];
    __syncthreads();
    const float* zz = ws + OFF_ZZ + (size_t)bo * 6912;
    // A: expand a1 -> this block's n1
    for (int r = 0; r < 2; ++r) {
        int e = t + 256 * r;        // a2*12 + k3
        if (e < 288) {
            float re = 0.f, im = 0.f;
#pragma unroll
            for (int a1 = 0; a1 < 24; ++a1) {
                float v = zz[a1 * 288 + e];      // coalesced, L2-hit
                int k1 = a1 < 12 ? a1 : a1 + 40;
                int m = (k1 * n1) & 63;
                re = fmaf(v, esh[2*m], re);      // e^{+i theta}
                im = fmaf(v, esh[2*m + 1], im);
            }
            c1s[2*e] = re; c1s[2*e + 1] = im;
        }
    }
    __syncthreads();
    // B: expand a2 -> n2
#pragma unroll
    for (int r = 0; r < 3; ++r) {
        int e = t + 256 * r;        // n2*12 + k3  (768 total = 3*256 exact)
        int n2 = e / 12, k3 = e - n2 * 12;
        float re = 0.f, im = 0.f;
#pragma unroll
        for (int a2 = 0; a2 < 24; ++a2) {
            float ur = c1s[a2*24 + 2*k3], ui = c1s[a2*24 + 2*k3 + 1];
            int k2 = a2 < 12 ? a2 : a2 + 40;
            int m = (k2 * n2) & 63;
            float c = esh[2*m], s = esh[2*m + 1];
            re += ur * c - ui * s;  // (ur + i ui)(c + i s)
            im += ur * s + ui * c;
        }
        c2s[2*e] = re; c2s[2*e + 1] = im;
    }
    // C twiddles into registers (n3 = t&63 invariant across the 16 rows)
    float rc[12], rs[12];
    {
        int n3 = t & 63, m = 0;
#pragma unroll
        for (int k3 = 0; k3 < 12; ++k3) {
            rc[k3] = esh[2*m]; rs[k3] = esh[2*m + 1];
            m = (m + n3) & 63;
        }
    }
    __syncthreads();
    // C: expand k3 -> n3, take Re, scale 1/64^3
    float* orow = out + (size_t)blk * 4096;
#pragma unroll
    for (int r = 0; r < 16; ++r) {
        int f = t + 256 * r;
        int n2 = f >> 6;            // wave-uniform
        const float* c2r = &c2s[n2 * 24];
        float acc = 0.f;
#pragma unroll
        for (int k3 = 0; k3 < 12; ++k3)
            acc += c2r[2*k3] * rc[k3] - c2r[2*k3 + 1] * rs[k3];
        orow[f] = acc * (1.f / 262144.f);
    }
}

extern "C" void kernel_launch(void* const* d_in, const int* in_sizes, int n_in,
                              void* d_out, int out_size, void* d_ws, size_t ws_size,
                              hipStream_t stream) {
    const float* x   = (const float*)d_in[0];   // [4,32,64,64,64]
    const float* wts = (const float*)d_in[1];   // [4,32,32,12,12,12,2]
    float* out = (float*)d_out;                 // [4,32,64,64,64]
    float* ws  = (float*)d_ws;
    if (ws_size < (size_t)WS_FLOATS * sizeof(float)) return;  // insufficient scratch

    k_init<<<1, 256, 0, stream>>>(ws);
    k_p12<<<8192, 256, 0, stream>>>(x, ws);
    k_p3<<<3072, 256, 0, stream>>>(ws);
    for (int q = 0; q < 4; ++q) {
        k_w<<<6912, 256, 0, stream>>>(wts, ws, q);
        k_e1<<<864, 256, 0, stream>>>(ws, q);
        k_e2<<<864, 256, 0, stream>>>(ws, q);
    }
    k_inv<<<8192, 256, 0, stream>>>(ws, out);
}

// Round 6
// 551.097 us; speedup vs baseline: 1.1668x; 1.0217x over previous
//
#include <hip/hip_runtime.h>
#include <math.h>

// ---------------------------------------------------------------------------
// SpectralConv3d via partial DFTs. B=4, Ci=Co=32, S=64, M=12.
// Only modes k1,k2 in {0..11, 52..63}, k3 in {0..11} survive.
// Twiddles via in-register rotation recurrence (drift ~1e-5 rel, harmless);
// LDS operand reads vectorized to ds_read_b128.
// ---------------------------------------------------------------------------

// ws layout (float offsets)
#define OFF_ES   0            // [64][2] cos/sin(2*pi*m/64)
#define OFF_C12P 128          // [12][12] cos+sin(2*pi*(k*z%12)/12)
#define OFF_C12M 272          // [12][12] sin-cos
#define OFF_U2   512
#define SZ_U2    4718592      // [128][64][24][12][2]  (forward only)
#define OFF_XHT  (OFF_U2 + SZ_U2)
#define SZ_XHT   1769472      // [128][24][24][12][2]
#define OFF_YP   (OFF_XHT + SZ_XHT)
#define SZ_Y     3538944      // [32][32][12][12][12][2] per corner (reused per q)
#define OFF_YM   (OFF_YP + SZ_Y)
#define OFF_ZB   (OFF_YM + SZ_Y)
#define SZ_ZB    442368       // [128][12][12][12][2]
#define OFF_ZZ   (OFF_ZB + SZ_ZB)
#define SZ_ZZ    884736       // [128][24][24][12] real
#define WS_FLOATS (OFF_ZZ + SZ_ZZ)   // 14,893,568 floats = ~59.6 MiB

__global__ void k_init(float* __restrict__ ws) {
    int t = threadIdx.x;
    if (t < 64) {
        double th = 6.283185307179586476925286766559 * (double)t / 64.0;
        ws[OFF_ES + 2*t]     = (float)cos(th);
        ws[OFF_ES + 2*t + 1] = (float)sin(th);
    }
    if (t < 144) {
        int k = t / 12, z = t % 12;
        double th = 6.283185307179586476925286766559 * (double)((k*z) % 12) / 12.0;
        double c = cos(th), s = sin(th);
        ws[OFF_C12P + t] = (float)(c + s);
        ws[OFF_C12M + t] = (float)(s - c);
    }
}

// P1+P2 fused: block = (bi*64 + n1).
// P1: thread owns n2=lane, a3 = w + 4r (wave-uniform); x row in VGPRs with
//     even/odd fold (halves MACs); twiddles by rotation recurrence.
// P2: intermediate us[a3][2*n2] (132-float rows, 16B aligned) read as b128
//     quads (2 complex per instr); twiddles by rotation recurrence.
__global__ __launch_bounds__(256) void k_p12(const float* __restrict__ x,
                                             float* __restrict__ ws) {
    __shared__ __align__(16) float xs[64 * 66];   // xs[n2*66 + n3]
    __shared__ __align__(16) float us[12 * 132];  // us[a3*132 + 2*n2] = re,im
    __shared__ float esh[128];
    int t = threadIdx.x;
    int lane = t & 63, w = t >> 6;
    int blk = blockIdx.x;
    const float* xrow = x + (size_t)blk * 4096;
    if (t < 128) esh[t] = ws[OFF_ES + t];
#pragma unroll
    for (int j = 0; j < 16; ++j) {
        int idx = t + 256 * j;                   // n2 = idx>>6, n3 = idx&63
        xs[(idx >> 6) * 66 + (idx & 63)] = xrow[idx];
    }
    __syncthreads();
    // ---- P1: contract n3 (64 -> 12 modes a3), e^{-i 2pi a3 n3/64} ----
    float x0 = xs[lane * 66 + 0], x32 = xs[lane * 66 + 32];
    float ev[31], od[31];
#pragma unroll
    for (int n = 1; n <= 31; ++n) {
        float a = xs[lane * 66 + n], b = xs[lane * 66 + 64 - n];
        ev[n - 1] = a + b;
        od[n - 1] = a - b;
    }
#pragma unroll
    for (int r = 0; r < 3; ++r) {
        int a3 = w + 4 * r;
        float cd = esh[2 * a3], sd = esh[2 * a3 + 1];   // step rotator
        float ar = x0 + ((a3 & 1) ? -x32 : x32);
        float ai = 0.f;
        float c = cd, s = sd;                            // twiddle at n=1
#pragma unroll
        for (int n = 0; n < 31; ++n) {
            ar = fmaf(ev[n], c, ar);
            ai = fmaf(-od[n], s, ai);
            float cn = fmaf(c, cd, -s * sd);
            float sn = fmaf(c, sd,  s * cd);
            c = cn; s = sn;
        }
        us[a3 * 132 + 2 * lane]     = ar;
        us[a3 * 132 + 2 * lane + 1] = ai;
    }
    __syncthreads();
    // ---- P2: contract n2 (64 -> 24 modes k2) ----
    float* uo = ws + OFF_U2 + (size_t)blk * 576;
    for (int rr = 0; rr < 2; ++rr) {
        int oidx = t + 256 * rr;                // a2*12 + a3
        if (oidx >= 288) break;
        int a2 = oidx / 12, a3 = oidx - a2 * 12;
        int k2 = a2 < 12 ? a2 : a2 + 40;
        float cd = esh[2 * k2], sd = esh[2 * k2 + 1];
        const float* urow = &us[a3 * 132];
        float ar = 0.f, ai = 0.f;
        float c = 1.f, s = 0.f;                 // twiddle at n2=0 (exact)
#pragma unroll 8
        for (int j = 0; j < 32; ++j) {          // n2 = 2j, 2j+1
            float4 uu = *(const float4*)&urow[4 * j];
            ar += uu.x * c + uu.y * s;          // U * e^{-i theta}
            ai += uu.y * c - uu.x * s;
            float c1 = fmaf(c, cd, -s * sd);
            float s1 = fmaf(c, sd,  s * cd);
            ar += uu.z * c1 + uu.w * s1;
            ai += uu.w * c1 - uu.z * s1;
            c = fmaf(c1, cd, -s1 * sd);
            s = fmaf(c1, sd,  s1 * cd);
        }
        uo[2 * oidx] = ar; uo[2 * oidx + 1] = ai;
    }
}

// P3: contract n1 (64 -> 24) and x_ht = U + e^{i psi} conj(U).
// block = bi*24 + a2. Same b128 + rotator structure as P2.
__global__ __launch_bounds__(256) void k_p3(float* __restrict__ ws) {
    __shared__ __align__(16) float us3[12 * 132];  // us3[a3*132 + 2*n1]
    __shared__ float esh[128];
    int t = threadIdx.x;
    int blk = blockIdx.x;
    int bi = blk / 24, a2 = blk - bi * 24;
    const float* u2 = ws + OFF_U2;
    for (int j = t; j < 1536; j += 256) {
        int n1 = j / 24, q = j - n1 * 24;        // q = 2*a3 + p
        float v = u2[(size_t)(bi * 64 + n1) * 576 + a2 * 24 + q];
        us3[(q >> 1) * 132 + 2 * n1 + (q & 1)] = v;
    }
    if (t < 128) esh[t] = ws[OFF_ES + t];
    __syncthreads();
    int k2 = a2 < 12 ? a2 : a2 + 40;
    float* xo = ws + OFF_XHT;
    for (int rr = 0; rr < 2; ++rr) {
        int oidx = t + 256 * rr;                 // a1*12 + a3
        if (oidx >= 288) break;
        int a1 = oidx / 12, a3 = oidx - a1 * 12;
        int k1 = a1 < 12 ? a1 : a1 + 40;
        float cd = esh[2 * k1], sd = esh[2 * k1 + 1];
        const float* urow = &us3[a3 * 132];
        float ar = 0.f, ai = 0.f;
        float c = 1.f, s = 0.f;
#pragma unroll 8
        for (int j = 0; j < 32; ++j) {           // n1 = 2j, 2j+1
            float4 uu = *(const float4*)&urow[4 * j];
            ar += uu.x * c + uu.y * s;
            ai += uu.y * c - uu.x * s;
            float c1 = fmaf(c, cd, -s * sd);
            float s1 = fmaf(c, sd,  s * cd);
            ar += uu.z * c1 + uu.w * s1;
            ai += uu.w * c1 - uu.z * s1;
            c = fmaf(c1, cd, -s1 * sd);
            s = fmaf(c1, sd,  s1 * cd);
        }
        int psi = (k1 + k2 + a3) & 63;
        float pc = esh[2 * psi], ps = esh[2 * psi + 1];
        float xr = ar + pc * ar + ps * ai;       // U + e^{i psi} conj(U)
        float xi = ai + ps * ar - pc * ai;
        size_t o = (((size_t)bi * 24 + a1) * 24 + a2) * 12 + a3;
        xo[2 * o] = xr; xo[2 * o + 1] = xi;
    }
}

// W: weight prep for corner q. Y = dht_z(w_q) (real); Yflip = w_q index-negated
// over (i,o,x); Yplus/minus = 0.5*(Y +/- Yflip).  thread = (i,o,x,y,k).
__global__ __launch_bounds__(256) void k_w(const float* __restrict__ wts,
                                           float* __restrict__ ws, int q) {
    __shared__ float cp[144], cm[144];
    int t = threadIdx.x;
    if (t < 144) { cp[t] = ws[OFF_C12P + t]; cm[t] = ws[OFF_C12M + t]; }
    __syncthreads();
    int flat = blockIdx.x * 256 + t;
    int k  = flat % 12;
    int y  = (flat / 12) % 12;
    int xx = (flat / 144) % 12;
    int o  = (flat / 1728) % 32;
    int i  = flat / 55296;
    size_t wb = ((((size_t)q * 32 + i) * 32 + o) * 12 + xx) * 12 + y;
    const float* wrow = wts + wb * 24;      // 12 z * (re,im)
    float Y = 0.f;
#pragma unroll
    for (int z = 0; z < 12; ++z)
        Y += wrow[2*z] * cp[k*12 + z] + wrow[2*z + 1] * cm[k*12 + z];
    int fi = (32 - i) & 31, fo = (32 - o) & 31, fx = (xx == 0) ? 0 : 12 - xx;
    size_t fwb = (((((size_t)q * 32 + fi) * 32 + fo) * 12 + fx) * 12 + y) * 12 + k;
    float wfr = wts[2*fwb], wfi = wts[2*fwb + 1];
    float* yp = ws + OFF_YP;
    float* ym = ws + OFF_YM;
    yp[2*flat]     = 0.5f * (Y + wfr);
    yp[2*flat + 1] = 0.5f * wfi;
    ym[2*flat]     = 0.5f * (Y - wfr);
    ym[2*flat + 1] = -0.5f * wfi;
}

// E1: Z[b,o,x,y,z] = sum_i x_q*Yplus + Xflip*Yminus  (all complex).
__global__ __launch_bounds__(256) void k_e1(float* __restrict__ ws, int q) {
    int t = threadIdx.x;
    int flat = blockIdx.x * 256 + t;        // (b,o,x,y,z)
    int z  = flat % 12;
    int y  = (flat / 12) % 12;
    int xx = (flat / 144) % 12;
    int o  = (flat / 1728) % 32;
    int b  = flat / 55296;
    int o1 = (q & 1) ? 12 : 0, o2 = (q & 2) ? 12 : 0;
    const float* xht = ws + OFF_XHT;
    const float* yp  = ws + OFF_YP;
    const float* ym  = ws + OFF_YM;
    int fb = (4 - b) & 3;
    int fx = (xx == 0) ? 0 : 12 - xx;
    float zr = 0.f, zi = 0.f;
    for (int i = 0; i < 32; ++i) {
        int fi = (32 - i) & 31;
        size_t xidx  = (((size_t)(b * 32 + i) * 24 + (o1 + xx)) * 24 + (o2 + y)) * 12 + z;
        size_t fxidx = (((size_t)(fb * 32 + fi) * 24 + (o1 + fx)) * 24 + (o2 + y)) * 12 + z;
        size_t yidx  = ((((size_t)i * 32 + o) * 12 + xx) * 12 + y) * 12 + z;
        float xr = xht[2*xidx],  xi2 = xht[2*xidx + 1];
        float fr = xht[2*fxidx], fim = xht[2*fxidx + 1];
        float pr = yp[2*yidx], pi = yp[2*yidx + 1];
        float mr = ym[2*yidx], mi = ym[2*yidx + 1];
        zr += xr * pr - xi2 * pi + fr * mr - fim * mi;
        zi += xr * pi + xi2 * pr + fr * mi + fim * mr;
    }
    float* zb = ws + OFF_ZB;
    zb[2*flat] = zr; zb[2*flat + 1] = zi;
}

// E2: (Re-Im of fft12_z(Z))/n, alpha(k3) folded in, scattered into zz.
__global__ __launch_bounds__(256) void k_e2(float* __restrict__ ws, int q) {
    __shared__ float cp[144], cm[144];
    int t = threadIdx.x;
    if (t < 144) { cp[t] = ws[OFF_C12P + t]; cm[t] = ws[OFF_C12M + t]; }
    __syncthreads();
    int flat = blockIdx.x * 256 + t;        // (bo,x,y,k)
    int k  = flat % 12;
    int y  = (flat / 12) % 12;
    int xx = (flat / 144) % 12;
    int bo = flat / 1728;
    const float* row = ws + OFF_ZB + (size_t)(flat - k) * 2;  // z=0 base
    float acc = 0.f;
#pragma unroll
    for (int z = 0; z < 12; ++z)
        acc += row[2*z] * cp[k*12 + z] + row[2*z + 1] * cm[k*12 + z];
    float scale = (k == 0 ? 1.f : 2.f) / 221184.f;  // alpha(k)/n
    int o1 = (q & 1) ? 12 : 0, o2 = (q & 2) ? 12 : 0;
    float* zz = ws + OFF_ZZ;
    zz[(((size_t)bo * 24 + (o1 + xx)) * 24 + (o2 + y)) * 12 + k] = acc * scale;
}

// INV: block = (bo*64 + n1). zz from global (L2-resident); C1/C2 in LDS.
__global__ __launch_bounds__(256) void k_inv(const float* __restrict__ ws,
                                             float* __restrict__ out) {
    __shared__ float c1s[576];      // [a2(24)][k3(12)][2]
    __shared__ float c2s[1536];     // [n2(64)][k3(12)][2]
    __shared__ float esh[128];
    int t = threadIdx.x;
    int blk = blockIdx.x;           // bo*64 + n1
    int bo = blk >> 6, n1 = blk & 63;
    if (t < 128) esh[t] = ws[OFF_ES + t];
    __syncthreads();
    const float* zz = ws + OFF_ZZ + (size_t)bo * 6912;
    for (int r = 0; r < 2; ++r) {
        int e = t + 256 * r;        // a2*12 + k3
        if (e < 288) {
            float re = 0.f, im = 0.f;
#pragma unroll
            for (int a1 = 0; a1 < 24; ++a1) {
                float v = zz[a1 * 288 + e];
                int k1 = a1 < 12 ? a1 : a1 + 40;
                int m = (k1 * n1) & 63;
                re = fmaf(v, esh[2*m], re);      // e^{+i theta}
                im = fmaf(v, esh[2*m + 1], im);
            }
            c1s[2*e] = re; c1s[2*e + 1] = im;
        }
    }
    __syncthreads();
#pragma unroll
    for (int r = 0; r < 3; ++r) {
        int e = t + 256 * r;        // n2*12 + k3
        int n2 = e / 12, k3 = e - n2 * 12;
        float re = 0.f, im = 0.f;
#pragma unroll
        for (int a2 = 0; a2 < 24; ++a2) {
            float ur = c1s[a2*24 + 2*k3], ui = c1s[a2*24 + 2*k3 + 1];
            int k2 = a2 < 12 ? a2 : a2 + 40;
            int m = (k2 * n2) & 63;
            float c = esh[2*m], s = esh[2*m + 1];
            re += ur * c - ui * s;  // (ur + i ui)(c + i s)
            im += ur * s + ui * c;
        }
        c2s[2*e] = re; c2s[2*e + 1] = im;
    }
    float rc[12], rs[12];
    {
        int n3 = t & 63, m = 0;
#pragma unroll
        for (int k3 = 0; k3 < 12; ++k3) {
            rc[k3] = esh[2*m]; rs[k3] = esh[2*m + 1];
            m = (m + n3) & 63;
        }
    }
    __syncthreads();
    float* orow = out + (size_t)blk * 4096;
#pragma unroll
    for (int r = 0; r < 16; ++r) {
        int f = t + 256 * r;
        int n2 = f >> 6;            // wave-uniform
        const float* c2r = &c2s[n2 * 24];
        float acc = 0.f;
#pragma unroll
        for (int k3 = 0; k3 < 12; ++k3)
            acc += c2r[2*k3] * rc[k3] - c2r[2*k3 + 1] * rs[k3];
        orow[f] = acc * (1.f / 262144.f);
    }
}

extern "C" void kernel_launch(void* const* d_in, const int* in_sizes, int n_in,
                              void* d_out, int out_size, void* d_ws, size_t ws_size,
                              hipStream_t stream) {
    const float* x   = (const float*)d_in[0];   // [4,32,64,64,64]
    const float* wts = (const float*)d_in[1];   // [4,32,32,12,12,12,2]
    float* out = (float*)d_out;                 // [4,32,64,64,64]
    float* ws  = (float*)d_ws;
    if (ws_size < (size_t)WS_FLOATS * sizeof(float)) return;  // insufficient scratch

    k_init<<<1, 256, 0, stream>>>(ws);
    k_p12<<<8192, 256, 0, stream>>>(x, ws);
    k_p3<<<3072, 256, 0, stream>>>(ws);
    for (int q = 0; q < 4; ++q) {
        k_w<<<6912, 256, 0, stream>>>(wts, ws, q);
        k_e1<<<864, 256, 0, stream>>>(ws, q);
        k_e2<<<864, 256, 0, stream>>>(ws, q);
    }
    k_inv<<<8192, 256, 0, stream>>>(ws, out);
}